// Round 3
// baseline (139.097 us; speedup 1.0000x reference)
//
#include <hip/hip_runtime.h>
#include <stdint.h>

// Rule 110 CA, batch=32, width=16384, 64 iterations, zero boundaries.
// idx = L + 2C + 4R, lookup[k]=(110>>k)&1  ==>  new = (L | C) & ~(L & C & R).
//
// Single fused kernel, trapezoidal width tiling + time-chunked stores:
//   - block = 256 threads = 4 independent waves, one (tile, time-chunk) each
//   - wave state = 2048 bits (1 u32/lane) covering cells [s-64, s+1984);
//     output tile = working bits [64, 1088) -> cells [s, s+1024)
//   - staleness: lane-0 carryL is fake 0, so working bits [0,t) are stale
//     after t steps; tile starts at bit 64 >= t for t<=64 -> safe
//   - wave q runs steps 0..16q+16, stores only t in (16q,16q+16] (q=0 also
//     stores t=0): 4x wave parallelism (8 waves/CU), 2.5x redundant compute
//   - cross-lane: 1-bit step carries via __ballot; store redistribution via
//     __shfl (ds_bpermute) -- NO LDS, NO barriers, so the 16 int4 stores per
//     step never hit a vmcnt(0) drain and stay in flight across steps.
// 136 MB of output stores = the HBM-write floor (~22 us at ~6 TB/s).

#define WIDTH  16384
#define BATCH  32
#define ITERS  64
#define TILE   1024
#define NTILE  (WIDTH / TILE)   // 16
#define CSTEP  16               // steps stored per chunk; 4 chunks = 64

__global__ __launch_bounds__(256) void ca_fused_kernel(
    const float* __restrict__ x, int* __restrict__ out)
{
    const int tid  = threadIdx.x;
    const int lane = tid & 63;
    const int q    = tid >> 6;             // time chunk 0..3
    const int tile = blockIdx.x;           // 0..15
    const int b    = blockIdx.y;           // 0..31
    const int s    = tile * TILE;

    // ---- pack initial state: lane owns working bits [lane*32, +32) ----
    const int p0 = s - 64 + lane * 32;
    const bool valid = (p0 >= 0) && (p0 < WIDTH);
    const uint32_t vmask = valid ? 0xffffffffu : 0u;

    uint32_t c = 0;
    if (valid) {
        const float4* xv = (const float4*)(x + (size_t)b * WIDTH + p0);
        #pragma unroll
        for (int i = 0; i < 8; ++i) {
            float4 f = xv[i];
            c |= (uint32_t)(f.x >= 0.5f) << (i * 4 + 0);
            c |= (uint32_t)(f.y >= 0.5f) << (i * 4 + 1);
            c |= (uint32_t)(f.z >= 0.5f) << (i * 4 + 2);
            c |= (uint32_t)(f.w >= 0.5f) << (i * 4 + 3);
        }
    }

    const int t_end   = CSTEP * q + CSTEP;             // inclusive last stored
    const int t_begin = (q == 0) ? 0 : (CSTEP * q + 1);

    int* outb = out + ((size_t)b * (ITERS + 1) + t_begin) * WIDTH + s;

    for (int t = 0; ; ++t) {
        if (t >= t_begin) {
            // unpack state t -> 1024 int32 (4 coalesced int4 stores/lane)
            int4* ov = (int4*)outb;
            #pragma unroll
            for (int j = 0; j < 4; ++j) {
                // lane i's 4 cells = working bits 64 + 256j + 4i .. +3
                uint32_t w   = (uint32_t)__shfl((int)c, 2 + j * 8 + (lane >> 3));
                uint32_t nib = w >> ((lane & 7) * 4);
                ov[j * 64 + lane] = make_int4((int)(nib & 1u), (int)((nib >> 1) & 1u),
                                              (int)((nib >> 2) & 1u), (int)((nib >> 3) & 1u));
            }
            outb += WIDTH;
        }
        if (t == t_end) break;

        // ---- one CA step; cross-lane 1-bit carries via 64-bit ballots ----
        uint64_t A  = __ballot((c & 1u) != 0);   // bit l = LSB of lane l
        uint64_t Bm = __ballot((c >> 31) != 0);  // bit l = MSB of lane l
        uint32_t carryL = (uint32_t)(((Bm << 1) >> lane) & 1ull);
        uint32_t carryR = (uint32_t)(((A  >> 1) >> lane) & 1ull);

        uint32_t l = (c << 1) | carryL;
        uint32_t r = (c >> 1) | (carryR << 31);
        c = ((l | c) & ~(l & c & r)) & vmask;    // vmask: outside array stays 0
    }
}

extern "C" void kernel_launch(void* const* d_in, const int* in_sizes, int n_in,
                              void* d_out, int out_size, void* d_ws, size_t ws_size,
                              hipStream_t stream)
{
    const float* x = (const float*)d_in[0];
    // d_in[1] = rule-110 lookup table -- fixed by setup, baked into the logic.
    (void)d_ws; (void)ws_size;

    dim3 grid(NTILE, BATCH);   // 512 blocks x 4 waves = 2048 waves (~8/CU)
    ca_fused_kernel<<<grid, 256, 0, stream>>>(x, (int*)d_out);
}